// Round 8
// baseline (413.267 us; speedup 1.0000x reference)
//
#include <hip/hip_runtime.h>
#include <hip/hip_bf16.h>

// CapsuleLayer dynamic routing. B=64, I=2048, D=16, J=32, K=16, routings=3.
// Proven: f32 in/out, ws >= 142.74 MB. Round-7 counters: route passes are
// 3x67 us = 80% of runtime, latency-bound (VALU 14%, HBM 14%, Occ 10.7%,
// VGPR 144 -> 3 waves/SIMD).
// Round 8: (a) route kernels split by name for attribution, (b) force
// <=128 VGPR via __launch_bounds__(256,4) -> 4 waves/SIMD, (c) 4+4 double-
// buffered prefetch with tight live ranges.

#define B_ 64
#define I_ 2048
#define D_ 16
#define J_ 32
#define K_ 16
#define JK 512  // J_*K_

typedef __attribute__((ext_vector_type(8))) short short8;
typedef __attribute__((ext_vector_type(4))) float float4v;

__device__ __forceinline__ unsigned short f2bf(float f) {
    union { float f; unsigned int i; } v;
    v.f = f;
    const unsigned int x = v.i;
    return (unsigned short)((x + 0x7fffu + ((x >> 16) & 1u)) >> 16);  // RNE
}

// ---------------------------------------------------------------------------
// Producer (MFMA): unchanged from round 7 (exited top-5).
// ---------------------------------------------------------------------------
__global__ __launch_bounds__(256)
void caps_produce(const float* __restrict__ x, const float* __restrict__ W,
                  unsigned short* __restrict__ uhat) {
    __shared__ unsigned short wlds[32 * 384];      // 24 KB
    __shared__ unsigned short zbuf[8];             // 16 B zeros
    __shared__ unsigned short ctile[4][16 * 264];  // 33 KB
    const int i = blockIdx.x;
    const int tid = threadIdx.x;

    if (tid < 8) zbuf[tid] = 0;

    {
        const float* wbase = W + (size_t)i * (J_ * D_ * K_);
        const int k = tid & 15;
#pragma unroll
        for (int half = 0; half < 2; ++half) {
            const int j = (tid >> 4) + half * 16;
            const float* p = wbase + j * (D_ * K_) + k;
            float vals[16];
#pragma unroll
            for (int d = 0; d < 16; ++d) vals[d] = p[d * K_];
            unsigned int pk[8];
#pragma unroll
            for (int q = 0; q < 8; ++q)
                pk[q] = ((unsigned int)f2bf(vals[2 * q + 1]) << 16) |
                        f2bf(vals[2 * q]);
            uint4* dst = reinterpret_cast<uint4*>(wlds + j * 384 + k * 24);
            uint4 w0; w0.x = pk[0]; w0.y = pk[1]; w0.z = pk[2]; w0.w = pk[3];
            uint4 w1; w1.x = pk[4]; w1.y = pk[5]; w1.z = pk[6]; w1.w = pk[7];
            dst[0] = w0; dst[1] = w1;
        }
    }
    __syncthreads();

    const int lane = tid & 63;
    const int wv = tid >> 6;
    const int quad = lane >> 4;
    const int l15 = lane & 15;
    const int b = wv * 16 + l15;

    union { uint4 u; short8 s; } bfrag;
    {
        const float* xp = x + ((size_t)b * I_ + i) * D_ + (quad & 1) * 8;
        const float4 x0 = reinterpret_cast<const float4*>(xp)[0];
        const float4 x1 = reinterpret_cast<const float4*>(xp)[1];
        bfrag.u.x = ((unsigned int)f2bf(x0.y) << 16) | f2bf(x0.x);
        bfrag.u.y = ((unsigned int)f2bf(x0.w) << 16) | f2bf(x0.z);
        bfrag.u.z = ((unsigned int)f2bf(x1.y) << 16) | f2bf(x1.x);
        bfrag.u.w = ((unsigned int)f2bf(x1.w) << 16) | f2bf(x1.z);
        if (quad >= 2) { bfrag.u.x = 0; bfrag.u.y = 0; bfrag.u.z = 0; bfrag.u.w = 0; }
    }

    const unsigned short* aptr =
        (quad >= 2) ? zbuf : (wlds + l15 * 24 + (quad & 1) * 8);
    const int astride = (quad >= 2) ? 0 : 384;
    unsigned short* ct = &ctile[wv][0];

    for (int jh = 0; jh < 2; ++jh) {
#pragma unroll
        for (int jj = 0; jj < 16; ++jj) {
            const int j = jh * 16 + jj;
            union { uint4 u; short8 s; } af;
            af.u = *reinterpret_cast<const uint4*>(aptr + (size_t)j * astride);
            float4v acc = {0.f, 0.f, 0.f, 0.f};
            acc = __builtin_amdgcn_mfma_f32_16x16x32_bf16(af.s, bfrag.s, acc,
                                                          0, 0, 0);
            uint2 pk;
            pk.x = ((unsigned int)f2bf(acc[1]) << 16) | f2bf(acc[0]);
            pk.y = ((unsigned int)f2bf(acc[3]) << 16) | f2bf(acc[2]);
            *reinterpret_cast<uint2*>(ct + l15 * 264 + jj * 16 + quad * 4) = pk;
        }
#pragma unroll
        for (int r = 0; r < 8; ++r) {
            const int bsub = r * 2 + (lane >> 5);
            const int c32 = lane & 31;
            const uint4 val = *reinterpret_cast<const uint4*>(
                ct + bsub * 264 + c32 * 8);
            *reinterpret_cast<uint4*>(
                uhat + ((size_t)(wv * 16 + bsub) * I_ + i) * JK + jh * 256 +
                c32 * 8) = val;
        }
    }
}

// ---------------------------------------------------------------------------
// Routing passes. 4096 waves (4/block) = 64 b x 64 chunks (32 i each).
// lane: kh = lane>>5, j = lane&31 -> u_hat[b, i, j, kh*8..+7] (one dwordx4,
// wave = 1KB dense). 4+4 double-buffered row prefetch. Softmax (route1):
// merge k-halves via shfl_xor(32), denom = 5 shfl within 32-half.
// __launch_bounds__(256,4): cap VGPR at 128 -> 4 waves/SIMD.
// ---------------------------------------------------------------------------
template <bool R0>
__device__ __forceinline__ void route_impl(
    const unsigned short* __restrict__ uhat, const float* __restrict__ vsum,
    float* __restrict__ spart) {
    const int lane = threadIdx.x & 63;
    const int wave = blockIdx.x * 4 + (threadIdx.x >> 6);
    const int bl = wave >> 6;
    const int chunk = wave & 63;
    const int kh = lane >> 5;
    const int j = lane & 31;
    const int jk8 = j * 16 + kh * 8;

    float v[8];
    if (!R0) {
        const float4* vp = reinterpret_cast<const float4*>(vsum + bl * JK + jk8);
        const float4 a0 = vp[0], a1 = vp[1];
        v[0] = a0.x; v[1] = a0.y; v[2] = a0.z; v[3] = a0.w;
        v[4] = a1.x; v[5] = a1.y; v[6] = a1.z; v[7] = a1.w;
    }

    float acc[8];
#pragma unroll
    for (int q = 0; q < 8; ++q) acc[q] = 0.f;

    const unsigned short* up = uhat + ((size_t)bl * I_ + chunk * 32) * JK + jk8;

    uint4 buf[2][4];
#pragma unroll
    for (int s = 0; s < 4; ++s)
        buf[0][s] = *reinterpret_cast<const uint4*>(up + (size_t)s * JK);

#pragma unroll
    for (int g = 0; g < 8; ++g) {
        const int cur = g & 1;
        if (g < 7) {
#pragma unroll
            for (int s = 0; s < 4; ++s)
                buf[cur ^ 1][s] = *reinterpret_cast<const uint4*>(
                    up + (size_t)((g + 1) * 4 + s) * JK);
        }
#pragma unroll
        for (int s = 0; s < 4; ++s) {
            const uint4 r = buf[cur][s];
            float u[8];
            {
                union { unsigned int i; float f; } t;
                t.i = r.x << 16;        u[0] = t.f;
                t.i = r.x & 0xffff0000u; u[1] = t.f;
                t.i = r.y << 16;        u[2] = t.f;
                t.i = r.y & 0xffff0000u; u[3] = t.f;
                t.i = r.z << 16;        u[4] = t.f;
                t.i = r.z & 0xffff0000u; u[5] = t.f;
                t.i = r.w << 16;        u[6] = t.f;
                t.i = r.w & 0xffff0000u; u[7] = t.f;
            }
            if (R0) {
#pragma unroll
                for (int q = 0; q < 8; ++q) acc[q] += u[q];
            } else {
                float p = 0.f;
#pragma unroll
                for (int q = 0; q < 8; ++q) p += u[q] * v[q];
                p += __shfl_xor(p, 32, 64);  // merge k-halves
                const float e = __expf(p);
                float S = e;
                S += __shfl_xor(S, 1, 64);
                S += __shfl_xor(S, 2, 64);
                S += __shfl_xor(S, 4, 64);
                S += __shfl_xor(S, 8, 64);
                S += __shfl_xor(S, 16, 64);
                const float c = e / S;
#pragma unroll
                for (int q = 0; q < 8; ++q) acc[q] += c * u[q];
            }
        }
    }

    float* sp = spart + ((size_t)chunk * B_ + bl) * JK + jk8;
    float4 o0, o1;
    o0.x = acc[0]; o0.y = acc[1]; o0.z = acc[2]; o0.w = acc[3];
    o1.x = acc[4]; o1.y = acc[5]; o1.z = acc[6]; o1.w = acc[7];
    reinterpret_cast<float4*>(sp)[0] = o0;
    reinterpret_cast<float4*>(sp)[1] = o1;
}

__global__ __launch_bounds__(256, 4)
void caps_route0(const unsigned short* __restrict__ uhat,
                 const float* __restrict__ vsum, float* __restrict__ spart) {
    route_impl<true>(uhat, vsum, spart);
}

__global__ __launch_bounds__(256, 4)
void caps_route1(const unsigned short* __restrict__ uhat,
                 const float* __restrict__ vsum, float* __restrict__ spart) {
    route_impl<false>(uhat, vsum, spart);
}

// ---------------------------------------------------------------------------
// Squash: grid = B_, 512 threads = (j = tid>>4, k = tid&15).
// ---------------------------------------------------------------------------
template <int MODE>
__global__ __launch_bounds__(512)
void caps_squash(const float* __restrict__ spart, float* __restrict__ vsum,
                 float* __restrict__ out) {
    const int bl = blockIdx.x;
    const int jk = threadIdx.x;
    float s = 0.f;
#pragma unroll 8
    for (int p = 0; p < 64; ++p)
        s += spart[((size_t)p * B_ + bl) * JK + jk];
    if (MODE == 0) s *= (1.f / 32.f);
    float q = s * s;
    q += __shfl_xor(q, 1, 64);
    q += __shfl_xor(q, 2, 64);
    q += __shfl_xor(q, 4, 64);
    q += __shfl_xor(q, 8, 64);
    const float scale = q / ((1.f + q) * sqrtf(q + 1e-7f));
    const float v = scale * s;
    if (MODE == 0)      vsum[bl * JK + jk] = v;
    else if (MODE == 1) vsum[bl * JK + jk] += v;
    else                out[(size_t)bl * JK + jk] = v;
}

// ---------------------------------------------------------------------------
extern "C" void kernel_launch(void* const* d_in, const int* in_sizes, int n_in,
                              void* d_out, int out_size, void* d_ws,
                              size_t ws_size, hipStream_t stream) {
    const float* x = (const float*)d_in[0];  // [B,I,D] f32
    const float* W = (const float*)d_in[1];  // [I,J,D,K] f32
    float* out = (float*)d_out;              // [B,J,K] f32

    char* ws = (char*)d_ws;
    unsigned short* uhat = (unsigned short*)ws;                // 128 MiB
    float* spart = (float*)(ws + (size_t)B_ * I_ * JK * 2);    // 8 MiB
    float* vsum = spart + (size_t)64 * B_ * JK;                // 128 KiB

    caps_produce<<<I_, 256, 0, stream>>>(x, W, uhat);

    caps_route0<<<1024, 256, 0, stream>>>(uhat, vsum, spart);
    caps_squash<0><<<B_, 512, 0, stream>>>(spart, vsum, out);

    caps_route1<<<1024, 256, 0, stream>>>(uhat, vsum, spart);
    caps_squash<1><<<B_, 512, 0, stream>>>(spart, vsum, out);

    caps_route1<<<1024, 256, 0, stream>>>(uhat, vsum, spart);
    caps_squash<2><<<B_, 512, 0, stream>>>(spart, vsum, out);
}

// Round 9
// 202.141 us; speedup vs baseline: 2.0445x; 2.0445x over previous
//
#include <hip/hip_runtime.h>
#include <hip/hip_bf16.h>

// CapsuleLayer dynamic routing. B=64, I=2048, D=16, J=32, K=16, routings=3.
// Proven: f32 in/out, ws >= 142.74 MB. Round-8 lesson: __launch_bounds__
// min-waves forced VGPR 64 -> 345 MB scratch spill per route dispatch. Never
// force; keep natural pressure < 128.
// Round 9:
//  - route0 DELETED: round-0 s = (1/32)*sum_i u_hat = streaming column sum
//    (caps_sum0, no softmax/shuffles/spart) + caps_squash0.
//  - route1: round-5 layout (lane=(i-parity,j), full 16-k row in lane,
//    softmax = 5 shfl in 32-half), 1-step prefetch, 64-thread blocks x 4096.
//  - produce: unchanged (round-7 MFMA + LDS-transpose stores).

#define B_ 64
#define I_ 2048
#define D_ 16
#define J_ 32
#define K_ 16
#define JK 512  // J_*K_

typedef __attribute__((ext_vector_type(8))) short short8;
typedef __attribute__((ext_vector_type(4))) float float4v;

__device__ __forceinline__ unsigned short f2bf(float f) {
    union { float f; unsigned int i; } v;
    v.f = f;
    const unsigned int x = v.i;
    return (unsigned short)((x + 0x7fffu + ((x >> 16) & 1u)) >> 16);  // RNE
}

__device__ __forceinline__ void unpack8(const uint4 r, float* u) {
    union { unsigned int i; float f; } t;
    t.i = r.x << 16;         u[0] = t.f;
    t.i = r.x & 0xffff0000u; u[1] = t.f;
    t.i = r.y << 16;         u[2] = t.f;
    t.i = r.y & 0xffff0000u; u[3] = t.f;
    t.i = r.z << 16;         u[4] = t.f;
    t.i = r.z & 0xffff0000u; u[5] = t.f;
    t.i = r.w << 16;         u[6] = t.f;
    t.i = r.w & 0xffff0000u; u[7] = t.f;
}

// ---------------------------------------------------------------------------
// Producer (MFMA): unchanged from round 7.
// ---------------------------------------------------------------------------
__global__ __launch_bounds__(256)
void caps_produce(const float* __restrict__ x, const float* __restrict__ W,
                  unsigned short* __restrict__ uhat) {
    __shared__ unsigned short wlds[32 * 384];      // 24 KB
    __shared__ unsigned short zbuf[8];             // 16 B zeros
    __shared__ unsigned short ctile[4][16 * 264];  // 33 KB
    const int i = blockIdx.x;
    const int tid = threadIdx.x;

    if (tid < 8) zbuf[tid] = 0;

    {
        const float* wbase = W + (size_t)i * (J_ * D_ * K_);
        const int k = tid & 15;
#pragma unroll
        for (int half = 0; half < 2; ++half) {
            const int j = (tid >> 4) + half * 16;
            const float* p = wbase + j * (D_ * K_) + k;
            float vals[16];
#pragma unroll
            for (int d = 0; d < 16; ++d) vals[d] = p[d * K_];
            unsigned int pk[8];
#pragma unroll
            for (int q = 0; q < 8; ++q)
                pk[q] = ((unsigned int)f2bf(vals[2 * q + 1]) << 16) |
                        f2bf(vals[2 * q]);
            uint4* dst = reinterpret_cast<uint4*>(wlds + j * 384 + k * 24);
            uint4 w0; w0.x = pk[0]; w0.y = pk[1]; w0.z = pk[2]; w0.w = pk[3];
            uint4 w1; w1.x = pk[4]; w1.y = pk[5]; w1.z = pk[6]; w1.w = pk[7];
            dst[0] = w0; dst[1] = w1;
        }
    }
    __syncthreads();

    const int lane = tid & 63;
    const int wv = tid >> 6;
    const int quad = lane >> 4;
    const int l15 = lane & 15;
    const int b = wv * 16 + l15;

    union { uint4 u; short8 s; } bfrag;
    {
        const float* xp = x + ((size_t)b * I_ + i) * D_ + (quad & 1) * 8;
        const float4 x0 = reinterpret_cast<const float4*>(xp)[0];
        const float4 x1 = reinterpret_cast<const float4*>(xp)[1];
        bfrag.u.x = ((unsigned int)f2bf(x0.y) << 16) | f2bf(x0.x);
        bfrag.u.y = ((unsigned int)f2bf(x0.w) << 16) | f2bf(x0.z);
        bfrag.u.z = ((unsigned int)f2bf(x1.y) << 16) | f2bf(x1.x);
        bfrag.u.w = ((unsigned int)f2bf(x1.w) << 16) | f2bf(x1.z);
        if (quad >= 2) { bfrag.u.x = 0; bfrag.u.y = 0; bfrag.u.z = 0; bfrag.u.w = 0; }
    }

    const unsigned short* aptr =
        (quad >= 2) ? zbuf : (wlds + l15 * 24 + (quad & 1) * 8);
    const int astride = (quad >= 2) ? 0 : 384;
    unsigned short* ct = &ctile[wv][0];

    for (int jh = 0; jh < 2; ++jh) {
#pragma unroll
        for (int jj = 0; jj < 16; ++jj) {
            const int j = jh * 16 + jj;
            union { uint4 u; short8 s; } af;
            af.u = *reinterpret_cast<const uint4*>(aptr + (size_t)j * astride);
            float4v acc = {0.f, 0.f, 0.f, 0.f};
            acc = __builtin_amdgcn_mfma_f32_16x16x32_bf16(af.s, bfrag.s, acc,
                                                          0, 0, 0);
            uint2 pk;
            pk.x = ((unsigned int)f2bf(acc[1]) << 16) | f2bf(acc[0]);
            pk.y = ((unsigned int)f2bf(acc[3]) << 16) | f2bf(acc[2]);
            *reinterpret_cast<uint2*>(ct + l15 * 264 + jj * 16 + quad * 4) = pk;
        }
#pragma unroll
        for (int r = 0; r < 8; ++r) {
            const int bsub = r * 2 + (lane >> 5);
            const int c32 = lane & 31;
            const uint4 val = *reinterpret_cast<const uint4*>(
                ct + bsub * 264 + c32 * 8);
            *reinterpret_cast<uint4*>(
                uhat + ((size_t)(wv * 16 + bsub) * I_ + i) * JK + jh * 256 +
                c32 * 8) = val;
        }
    }
}

// ---------------------------------------------------------------------------
// Round-0 column sum (uniform coupling): grid = 64 b x 4 q, 256 threads.
// Wave w sums i in [q*512 + w*128, +128); lane owns jk8 = lane*8 (16B dense,
// wave instr = 1KB). LDS-combine 4 waves -> spart2[b][q][512].
// Pure load+add streaming; no shuffles.
// ---------------------------------------------------------------------------
__global__ __launch_bounds__(256)
void caps_sum0(const unsigned short* __restrict__ uhat,
               float* __restrict__ spart2) {
    __shared__ float part[4][512];
    const int bq = blockIdx.x;
    const int b = bq >> 2, q = bq & 3;
    const int lane = threadIdx.x & 63;
    const int w = threadIdx.x >> 6;

    const unsigned short* up =
        uhat + ((size_t)b * I_ + q * 512 + w * 128) * JK + lane * 8;

    float acc[8];
#pragma unroll
    for (int k = 0; k < 8; ++k) acc[k] = 0.f;

    for (int ii = 0; ii < 128; ii += 4) {
        uint4 r[4];
#pragma unroll
        for (int s = 0; s < 4; ++s)
            r[s] = *reinterpret_cast<const uint4*>(up + (size_t)(ii + s) * JK);
#pragma unroll
        for (int s = 0; s < 4; ++s) {
            float u[8];
            unpack8(r[s], u);
#pragma unroll
            for (int k = 0; k < 8; ++k) acc[k] += u[k];
        }
    }

    float4 o0, o1;
    o0.x = acc[0]; o0.y = acc[1]; o0.z = acc[2]; o0.w = acc[3];
    o1.x = acc[4]; o1.y = acc[5]; o1.z = acc[6]; o1.w = acc[7];
    reinterpret_cast<float4*>(&part[w][lane * 8])[0] = o0;
    reinterpret_cast<float4*>(&part[w][lane * 8])[1] = o1;
    __syncthreads();

    const int t = threadIdx.x;  // 256 threads x 2 jk
#pragma unroll
    for (int e = 0; e < 2; ++e) {
        const int jk = t * 2 + e;
        spart2[(size_t)bq * 512 + jk] =
            part[0][jk] + part[1][jk] + part[2][jk] + part[3][jk];
    }
}

// Squash for round 0: reads spart2[b][q][jk], applies 1/32.
__global__ __launch_bounds__(512)
void caps_squash0(const float* __restrict__ spart2, float* __restrict__ vsum) {
    const int bl = blockIdx.x;
    const int jk = threadIdx.x;
    float s = spart2[(size_t)(bl * 4 + 0) * 512 + jk] +
              spart2[(size_t)(bl * 4 + 1) * 512 + jk] +
              spart2[(size_t)(bl * 4 + 2) * 512 + jk] +
              spart2[(size_t)(bl * 4 + 3) * 512 + jk];
    s *= (1.f / 32.f);
    float q = s * s;
    q += __shfl_xor(q, 1, 64);
    q += __shfl_xor(q, 2, 64);
    q += __shfl_xor(q, 4, 64);
    q += __shfl_xor(q, 8, 64);
    const float scale = q / ((1.f + q) * sqrtf(q + 1e-7f));
    vsum[bl * JK + jk] = scale * s;
}

// ---------------------------------------------------------------------------
// Softmax routing pass: 4096 one-wave blocks = 64 b x 64 chunks (32 i).
// lane: h = lane>>5 (i parity), j = lane&31 -> owns u_hat[b,i,j,0:16] (32B).
// In-lane 16-dot; softmax denom = 5 shfl within the 32-half (its 32 lanes
// share one i). 1-step (2x uint4) prefetch; natural VGPR (~80), no forcing.
// ---------------------------------------------------------------------------
__global__ __launch_bounds__(64)
void caps_route1(const unsigned short* __restrict__ uhat,
                 const float* __restrict__ vsum, float* __restrict__ spart) {
    const int lane = threadIdx.x;
    const int bl = blockIdx.x >> 6;
    const int chunk = blockIdx.x & 63;
    const int h = lane >> 5;
    const int j = lane & 31;

    float v[16];
    {
        const float4* vp =
            reinterpret_cast<const float4*>(vsum + bl * JK + j * 16);
        const float4 a0 = vp[0], a1 = vp[1], a2 = vp[2], a3 = vp[3];
        v[0] = a0.x; v[1] = a0.y; v[2] = a0.z; v[3] = a0.w;
        v[4] = a1.x; v[5] = a1.y; v[6] = a1.z; v[7] = a1.w;
        v[8] = a2.x; v[9] = a2.y; v[10] = a2.z; v[11] = a2.w;
        v[12] = a3.x; v[13] = a3.y; v[14] = a3.z; v[15] = a3.w;
    }

    float acc[16];
#pragma unroll
    for (int k = 0; k < 16; ++k) acc[k] = 0.f;

    const unsigned short* up =
        uhat + ((size_t)bl * I_ + chunk * 32 + h) * JK + j * 16;

    uint4 c0 = reinterpret_cast<const uint4*>(up)[0];
    uint4 c1 = reinterpret_cast<const uint4*>(up)[1];

#pragma unroll 4
    for (int t = 0; t < 16; ++t) {
        uint4 n0, n1;
        if (t < 15) {
            const uint4* np =
                reinterpret_cast<const uint4*>(up + (size_t)(t + 1) * 2 * JK);
            n0 = np[0];
            n1 = np[1];
        }
        float u[16];
        unpack8(c0, u);
        unpack8(c1, u + 8);
        float p = 0.f;
#pragma unroll
        for (int k = 0; k < 16; ++k) p += u[k] * v[k];
        const float e = __expf(p);  // |p| bounded; f32-safe
        float S = e;                // denom over the 32 j's of this half
        S += __shfl_xor(S, 1, 64);
        S += __shfl_xor(S, 2, 64);
        S += __shfl_xor(S, 4, 64);
        S += __shfl_xor(S, 8, 64);
        S += __shfl_xor(S, 16, 64);
        const float c = e / S;
#pragma unroll
        for (int k = 0; k < 16; ++k) acc[k] += c * u[k];
        c0 = n0;
        c1 = n1;
    }

    // merge the two i-parity halves (same (b,j,k))
#pragma unroll
    for (int k = 0; k < 16; ++k) acc[k] += __shfl_xor(acc[k], 32, 64);

    if (h == 0) {
        float* sp = spart + ((size_t)chunk * B_ + bl) * JK + j * 16;
#pragma unroll
        for (int q = 0; q < 4; ++q) {
            float4 o;
            o.x = acc[q * 4 + 0]; o.y = acc[q * 4 + 1];
            o.z = acc[q * 4 + 2]; o.w = acc[q * 4 + 3];
            reinterpret_cast<float4*>(sp)[q] = o;
        }
    }
}

// ---------------------------------------------------------------------------
// Squash for rounds 1,2: reduce spart[64][B][512].
// MODE 1: vsum += v.  MODE 2: out = v.
// ---------------------------------------------------------------------------
template <int MODE>
__global__ __launch_bounds__(512)
void caps_squash(const float* __restrict__ spart, float* __restrict__ vsum,
                 float* __restrict__ out) {
    const int bl = blockIdx.x;
    const int jk = threadIdx.x;
    float s = 0.f;
#pragma unroll 8
    for (int p = 0; p < 64; ++p)
        s += spart[((size_t)p * B_ + bl) * JK + jk];
    float q = s * s;
    q += __shfl_xor(q, 1, 64);
    q += __shfl_xor(q, 2, 64);
    q += __shfl_xor(q, 4, 64);
    q += __shfl_xor(q, 8, 64);
    const float scale = q / ((1.f + q) * sqrtf(q + 1e-7f));
    const float v = scale * s;
    if (MODE == 1) vsum[bl * JK + jk] += v;
    else           out[(size_t)bl * JK + jk] = v;
}

// ---------------------------------------------------------------------------
extern "C" void kernel_launch(void* const* d_in, const int* in_sizes, int n_in,
                              void* d_out, int out_size, void* d_ws,
                              size_t ws_size, hipStream_t stream) {
    const float* x = (const float*)d_in[0];  // [B,I,D] f32
    const float* W = (const float*)d_in[1];  // [I,J,D,K] f32
    float* out = (float*)d_out;              // [B,J,K] f32

    char* ws = (char*)d_ws;
    unsigned short* uhat = (unsigned short*)ws;                // 128 MiB
    float* spart = (float*)(ws + (size_t)B_ * I_ * JK * 2);    // 8 MiB
    float* vsum = spart + (size_t)64 * B_ * JK;                // 128 KiB

    caps_produce<<<I_, 256, 0, stream>>>(x, W, uhat);

    caps_sum0<<<256, 256, 0, stream>>>(uhat, spart);
    caps_squash0<<<B_, 512, 0, stream>>>(spart, vsum);

    caps_route1<<<4096, 64, 0, stream>>>(uhat, vsum, spart);
    caps_squash<1><<<B_, 512, 0, stream>>>(spart, vsum, out);

    caps_route1<<<4096, 64, 0, stream>>>(uhat, vsum, spart);
    caps_squash<2><<<B_, 512, 0, stream>>>(spart, vsum, out);
}